// Round 8
// baseline (544.135 us; speedup 1.0000x reference)
//
#include <hip/hip_runtime.h>
#include <hip/hip_bf16.h>

typedef __bf16 bf16_t;
typedef bf16_t bf16x8 __attribute__((ext_vector_type(8)));
typedef float f32x4 __attribute__((ext_vector_type(4)));
typedef unsigned short u16;
typedef unsigned int u32;

static constexpr int kHW = 192 * 320;          // 61440
static constexpr float kC = 4.77464829275686f; // 30 / (2*pi)

__device__ __forceinline__ u16 f2bf(float f) {
  u32 u = __float_as_uint(f);
  return (u16)((u + 0x7FFFu + ((u >> 16) & 1u)) >> 16);
}

__device__ __forceinline__ u32 pack2(float a, float b) {
  __hip_bfloat162 h = __float22bfloat162_rn(make_float2(a, b));
  union { __hip_bfloat162 h2; u32 u; } cv;
  cv.h2 = h;
  return cv.u;
}

// LDS-visibility-only barrier: leaves global loads (weight prefetch) in flight.
__device__ __forceinline__ void lds_barrier() {
  __asm__ volatile("s_waitcnt lgkmcnt(0)\n\ts_barrier" ::: "memory");
}

// ---- d_ws layout ----
static constexpr int OFF_W0 = 0;        // [64][64] (t-col folded to bias)
static constexpr int OFF_W1 = 4096;     // [64][64]
static constexpr int OFF_W2 = 8192;     // [256][64]
static constexpr int OFF_W3 = 24576;    // [256][256]
static constexpr int OFF_W4 = 90112;    // [256][256]
static constexpr int OFF_W5 = 155648;   // [64][256] (not scaled)
static constexpr int W_TOTAL = 172032;
static constexpr int B_TOTAL = 1024;
static constexpr size_t FEAT_BYTE_OFF = 348160;
static constexpr size_t WS_NEED = FEAT_BYTE_OFF + (size_t)1920 * 8192;

__global__ void convert_weights(const float* __restrict__ w0, const float* __restrict__ w1,
                                const float* __restrict__ w2, const float* __restrict__ w3,
                                const float* __restrict__ w4, const float* __restrict__ w5,
                                const float* __restrict__ b0, const float* __restrict__ b1,
                                const float* __restrict__ b2, const float* __restrict__ b3,
                                const float* __restrict__ b4, const float* __restrict__ b5,
                                u16* __restrict__ wb, float* __restrict__ bws) {
  int i = blockIdx.x * 256 + threadIdx.x;
  if (i < W_TOTAL) {
    float v, s = kC;
    if (i < OFF_W1)      { int o = i >> 6, k = i & 63; v = w0[o * 65 + k]; }
    else if (i < OFF_W2) { v = w1[i - OFF_W1]; }
    else if (i < OFF_W3) { v = w2[i - OFF_W2]; }
    else if (i < OFF_W4) { v = w3[i - OFF_W3]; }
    else if (i < OFF_W5) { v = w4[i - OFF_W4]; }
    else                 { v = w5[i - OFF_W5]; s = 1.0f; }
    wb[i] = f2bf(v * s);
  } else {
    int j = i - W_TOTAL;
    float v;
    if (j < 64)       v = kC * b0[j];
    else if (j < 128) v = kC * w0[(j - 64) * 65 + 64];
    else if (j < 192) v = kC * b1[j - 128];
    else if (j < 448) v = kC * b2[j - 192];
    else if (j < 704) v = kC * b3[j - 448];
    else if (j < 960) v = kC * b4[j - 704];
    else              v = b5[j - 960];
    bws[j] = v;
  }
}

// Pre-transpose feat into the swizzled bf16 image (the exact L0 A-frag layout).
__global__ void convert_feat(const float* __restrict__ feat, u16* __restrict__ featT) {
  const int chunk = blockIdx.x;
  const int bq  = chunk / 960;
  const int hw0 = (chunk % 960) * 64;
  const int tid = threadIdx.x;
  const int p   = tid & 63;
  const int gg  = tid >> 6;
  const float* fbase = feat + (size_t)bq * 64 * kHW + hw0 + p;
  u16* img = featT + (size_t)chunk * 4096;
#pragma unroll
  for (int j = 0; j < 2; ++j) {
    const int g = gg * 2 + j;
    float v[8];
#pragma unroll
    for (int e = 0; e < 8; ++e) v[e] = fbase[(size_t)(g * 8 + e) * kHW];
    uint4 pk;
    pk.x = pack2(v[0], v[1]);
    pk.y = pack2(v[2], v[3]);
    pk.z = pack2(v[4], v[5]);
    pk.w = pack2(v[6], v[7]);
    *reinterpret_cast<uint4*>(img + p * 64 + ((g ^ (p & 7)) * 8)) = pk;
  }
}

template<int RSO>
__device__ __forceinline__ void epilogue_sin(f32x4 acc, u16* outb, int p, int g,
                                             int quad, int sw) {
  float s0 = __builtin_amdgcn_sinf(__builtin_amdgcn_fractf(acc[0]));
  float s1 = __builtin_amdgcn_sinf(__builtin_amdgcn_fractf(acc[1]));
  float s2 = __builtin_amdgcn_sinf(__builtin_amdgcn_fractf(acc[2]));
  float s3 = __builtin_amdgcn_sinf(__builtin_amdgcn_fractf(acc[3]));
  uint2 v;
  v.x = pack2(s0, s1);
  v.y = pack2(s2, s3);
  *reinterpret_cast<uint2*>(outb + p * RSO + ((g ^ sw) * 8) + (quad & 1) * 4) = v;
}

__device__ __forceinline__ f32x4 mf(bf16x8 a, bf16x8 b, f32x4 c) {
  return __builtin_amdgcn_mfma_f32_16x16x32_bf16(a, b, c, 0, 0, 0);
}

// R8: fold the 3 time-steps into the block (grid 960). t only enters via the
// L0 bias (bv0 = cb + t*cw), so all weight fragments are loaded at c==0 and
// reused for c=1,2 -> weight L2 traffic /3 (967->322 MB; was 58% of per-XCD
// L2 read BW). Register peak unchanged: wf3/wf4 were already co-live in R7's
// L3; guards only skip reloads. Cross-iteration LDS hazards are ordered by
// the existing per-phase barriers (L0(c+1) writes Y ⊥ A32; L1(c+1) writes X
// after the post-L0 barrier which transitively follows every wave's L5(c)).
template<bool PRE>
__global__ __attribute__((amdgpu_waves_per_eu(2, 2)))
void __launch_bounds__(512)
siren_main(const float* __restrict__ feat, const float* __restrict__ times,
           const u16* __restrict__ wb, const float* __restrict__ bws,
           const u16* __restrict__ featT, float* __restrict__ out) {
  __shared__ __align__(16) u16 A32[128 * 256];   // 64 KB
  __shared__ __align__(16) u16 B32[128 * 256];   // 64 KB
  u16* X = B32;          // 128x64 compact (stride 64), aliases B32 (dead by L3)
  u16* Y = B32 + 8192;

  const int tid   = threadIdx.x;
  const int pair  = blockIdx.x;    // 0..959: covers old chunks 2*pair, 2*pair+1
  const int bq    = pair / 480;
  const int hw0   = (pair % 480) * 128;
  const int wave  = tid >> 6;      // 0..7
  const int lane  = tid & 63;
  const int l15   = lane & 15;
  const int quad  = lane >> 4;
  const int sw    = l15 & 7;
  const int wlo   = wave & 3;      // col tile for 64-wide layers / L5
  const int p0    = (wave >> 2) * 4; // 64-wide layers / L5: pts p0..p0+3

  // ---------- helpers ----------
  auto read_af8 = [&](bf16x8 (&af)[8], const u16* in, int pt) {
#pragma unroll
    for (int ks = 0; ks < 8; ++ks)
      af[ks] = *reinterpret_cast<const bf16x8*>(
          in + (pt * 16 + l15) * 256 + (((ks * 4 + quad) ^ sw) * 8));
  };
  auto read_af2 = [&](bf16x8 (&af)[2], const u16* in, int pt) {
#pragma unroll
    for (int ks = 0; ks < 2; ++ks)
      af[ks] = *reinterpret_cast<const bf16x8*>(
          in + (pt * 16 + l15) * 64 + (((ks * 4 + quad) ^ sw) * 8));
  };
  // Full 256-wide weight fragment for this wave's 32 rows: 16 bf16x8 = 64 regs.
  auto load_wf16 = [&](bf16x8 (&wf)[2][8], const u16* wbase) {
#pragma unroll
    for (int ot = 0; ot < 2; ++ot)
#pragma unroll
      for (int ks = 0; ks < 8; ++ks)
        wf[ot][ks] = *reinterpret_cast<const bf16x8*>(
            wbase + ((wave * 2 + ot) * 16 + l15) * 256 + ks * 32 + quad * 8);
  };
  auto load_bv2 = [&](f32x4 (&bv)[2], const float* bg) {
#pragma unroll
    for (int ot = 0; ot < 2; ++ot)
      bv[ot] = *reinterpret_cast<const f32x4*>(bg + (wave * 2 + ot) * 16 + quad * 4);
  };
  // Two pt-tiles interleaved: 4 independent chains (2 ot x 2 pt).
  auto mfma_pair2 = [&](f32x4 (&accA)[2], f32x4 (&accB)[2], bf16x8 (&wf)[2][8],
                        bf16x8 (&afA)[8], bf16x8 (&afB)[8], const f32x4 (&bv)[2]) {
#pragma unroll
    for (int ot = 0; ot < 2; ++ot) { accA[ot] = bv[ot]; accB[ot] = bv[ot]; }
#pragma unroll
    for (int ks = 0; ks < 8; ++ks)
#pragma unroll
      for (int ot = 0; ot < 2; ++ot) {
        accA[ot] = mf(wf[ot][ks], afA[ks], accA[ot]);
        accB[ot] = mf(wf[ot][ks], afB[ks], accB[ot]);
      }
  };
  auto epi_pt2 = [&](f32x4 (&acc)[2], u16* outb, int pt) {
#pragma unroll
    for (int ot = 0; ot < 2; ++ot)
      epilogue_sin<256>(acc[ot], outb, pt * 16 + l15,
                        (wave * 2 + ot) * 2 + (quad >> 1), quad, sw);
  };

  // ---------- persistent weight registers (loaded at c==0 only) ----------
  bf16x8 wf0[2], wf1[2];
  f32x4  cb, cw, bv1;
  bf16x8 wf2[2][2];
  f32x4  bv2[2];
  bf16x8 wf3[2][8];
  f32x4  bv3[2];
  bf16x8 wf4[2][8];
  f32x4  bv4[2];
  bf16x8 wf5[8];
  f32x4  bv5;

  for (int c = 0; c < 3; ++c) {
    const float t = times[c];
    if (c == 0) {
#pragma unroll
      for (int ks = 0; ks < 2; ++ks) {
        wf0[ks] = *reinterpret_cast<const bf16x8*>(wb + OFF_W0 + (wlo * 16 + l15) * 64 + ks * 32 + quad * 8);
        wf1[ks] = *reinterpret_cast<const bf16x8*>(wb + OFF_W1 + (wlo * 16 + l15) * 64 + ks * 32 + quad * 8);
      }
      cb  = *reinterpret_cast<const f32x4*>(bws + wlo * 16 + quad * 4);
      cw  = *reinterpret_cast<const f32x4*>(bws + 64 + wlo * 16 + quad * 4);
      bv1 = *reinterpret_cast<const f32x4*>(bws + 128 + wlo * 16 + quad * 4);
    }
    f32x4 bv0;
#pragma unroll
    for (int r = 0; r < 4; ++r) bv0[r] = cb[r] + t * cw[r];

    // ---------- L0: featT(global) or X(LDS) -> Y (wave: pts p0..p0+3, col wlo) ----------
    if constexpr (PRE) {
      const u16* fsrc = featT + (size_t)pair * 8192;
      bf16x8 a[4][2];
#pragma unroll
      for (int p = 0; p < 4; ++p)
#pragma unroll
        for (int ks = 0; ks < 2; ++ks)
          a[p][ks] = *reinterpret_cast<const bf16x8*>(
              fsrc + ((p0 + p) * 16 + l15) * 64 + (((ks * 4 + quad) ^ sw) * 8));
      if (c == 0) {
#pragma unroll
        for (int ot = 0; ot < 2; ++ot)
#pragma unroll
          for (int ks = 0; ks < 2; ++ks)
            wf2[ot][ks] = *reinterpret_cast<const bf16x8*>(
                wb + OFF_W2 + ((wave * 2 + ot) * 16 + l15) * 64 + ks * 32 + quad * 8);
        load_bv2(bv2, bws + 192);
      }

      f32x4 accp[4];
#pragma unroll
      for (int p = 0; p < 4; ++p) accp[p] = bv0;
#pragma unroll
      for (int ks = 0; ks < 2; ++ks)
#pragma unroll
        for (int p = 0; p < 4; ++p) accp[p] = mf(wf0[ks], a[p][ks], accp[p]);
#pragma unroll
      for (int p = 0; p < 4; ++p)
        epilogue_sin<64>(accp[p], Y, (p0 + p) * 16 + l15, wlo * 2 + (quad >> 1), quad, sw);
    } else {
      // fallback: stage 128px into X, then classic LDS path (restaged per c)
      {
        const int p  = tid & 127;    // 0..127
        const int gg = tid >> 7;     // 0..3
        const float* fbase = feat + (size_t)bq * 64 * kHW + hw0 + p;
#pragma unroll
        for (int j = 0; j < 2; ++j) {
          const int g = gg * 2 + j;
          float v[8];
#pragma unroll
          for (int e = 0; e < 8; ++e) v[e] = fbase[(size_t)(g * 8 + e) * kHW];
          uint4 pk;
          pk.x = pack2(v[0], v[1]);
          pk.y = pack2(v[2], v[3]);
          pk.z = pack2(v[4], v[5]);
          pk.w = pack2(v[6], v[7]);
          *reinterpret_cast<uint4*>(X + p * 64 + ((g ^ (p & 7)) * 8)) = pk;
        }
      }
      lds_barrier();
      if (c == 0) {
#pragma unroll
        for (int ot = 0; ot < 2; ++ot)
#pragma unroll
          for (int ks = 0; ks < 2; ++ks)
            wf2[ot][ks] = *reinterpret_cast<const bf16x8*>(
                wb + OFF_W2 + ((wave * 2 + ot) * 16 + l15) * 64 + ks * 32 + quad * 8);
        load_bv2(bv2, bws + 192);
      }
#pragma unroll
      for (int p = 0; p < 4; ++p) {
        bf16x8 a[2];
        read_af2(a, X, p0 + p);
        f32x4 acc = bv0;
        acc = mf(wf0[0], a[0], acc); acc = mf(wf0[1], a[1], acc);
        epilogue_sin<64>(acc, Y, (p0 + p) * 16 + l15, wlo * 2 + (quad >> 1), quad, sw);
      }
    }
    lds_barrier();

    // ---------- L1: Y -> X ; c==0: issue FULL wf3 (window = L1+L2) ----------
    {
      bf16x8 a[4][2];
      read_af2(a[0], Y, p0);
      read_af2(a[1], Y, p0 + 1);
      read_af2(a[2], Y, p0 + 2);
      read_af2(a[3], Y, p0 + 3);
      if (c == 0) {
        load_wf16(wf3, wb + OFF_W3);
        load_bv2(bv3, bws + 448);
      }
      f32x4 accp[4];
#pragma unroll
      for (int p = 0; p < 4; ++p) accp[p] = bv1;
#pragma unroll
      for (int ks = 0; ks < 2; ++ks)
#pragma unroll
        for (int p = 0; p < 4; ++p) accp[p] = mf(wf1[ks], a[p][ks], accp[p]);
#pragma unroll
      for (int p = 0; p < 4; ++p)
        epilogue_sin<64>(accp[p], X, (p0 + p) * 16 + l15, wlo * 2 + (quad >> 1), quad, sw);
    }
    lds_barrier();

    // ---------- L2: X -> A32 (all 8 pts per wave, 2 out tiles) ----------
    {
      bf16x8 aA[2], aB[2];
      read_af2(aA, X, 0);
      read_af2(aB, X, 1);
      f32x4 accA[2], accB[2];
#pragma unroll
      for (int pp = 0; pp < 4; ++pp) {
#pragma unroll
        for (int ot = 0; ot < 2; ++ot) { accA[ot] = bv2[ot]; accB[ot] = bv2[ot]; }
#pragma unroll
        for (int ks = 0; ks < 2; ++ks)
#pragma unroll
          for (int ot = 0; ot < 2; ++ot) {
            accA[ot] = mf(wf2[ot][ks], aA[ks], accA[ot]);
            accB[ot] = mf(wf2[ot][ks], aB[ks], accB[ot]);
          }
        if (pp < 3) {
          read_af2(aA, X, pp * 2 + 2);
          read_af2(aB, X, pp * 2 + 3);
        }
        epi_pt2(accA, A32, pp * 2);
        epi_pt2(accB, A32, pp * 2 + 1);
      }
    }
    lds_barrier();

    // ---------- L3: A32 -> B32 ; c==0: mid-issue FULL wf4 ----------
    {
      bf16x8 afA[8], afB[8];
      f32x4 accA[2], accB[2];
      read_af8(afA, A32, 0);
      read_af8(afB, A32, 1);
      // pair 0
      mfma_pair2(accA, accB, wf3, afA, afB, bv3);
      read_af8(afA, A32, 2);
      read_af8(afB, A32, 3);
      epi_pt2(accA, B32, 0);
      epi_pt2(accB, B32, 1);
      // pair 1
      mfma_pair2(accA, accB, wf3, afA, afB, bv3);
      read_af8(afA, A32, 4);
      read_af8(afB, A32, 5);
      if (c == 0) {
        // wf4 full prefetch: pinned so it can't hoist above pair-0/1 (reg peak).
        __builtin_amdgcn_sched_barrier(0);
        load_wf16(wf4, wb + OFF_W4);
        load_bv2(bv4, bws + 704);
      }
      epi_pt2(accA, B32, 2);
      epi_pt2(accB, B32, 3);
      // pair 2
      mfma_pair2(accA, accB, wf3, afA, afB, bv3);
      read_af8(afA, A32, 6);
      read_af8(afB, A32, 7);
      epi_pt2(accA, B32, 4);
      epi_pt2(accB, B32, 5);
      // pair 3
      mfma_pair2(accA, accB, wf3, afA, afB, bv3);
      epi_pt2(accA, B32, 6);
      epi_pt2(accB, B32, 7);
    }
    lds_barrier();

    // ---------- L4: B32 -> A32 ; c==0: mid-issue wf5 (32 regs) ----------
    {
      bf16x8 afA[8], afB[8];
      f32x4 accA[2], accB[2];
      read_af8(afA, B32, 0);
      read_af8(afB, B32, 1);
      // pair 0
      mfma_pair2(accA, accB, wf4, afA, afB, bv4);
      read_af8(afA, B32, 2);
      read_af8(afB, B32, 3);
      epi_pt2(accA, A32, 0);
      epi_pt2(accB, A32, 1);
      // pair 1
      mfma_pair2(accA, accB, wf4, afA, afB, bv4);
      read_af8(afA, B32, 4);
      read_af8(afB, B32, 5);
      if (c == 0) {
        __builtin_amdgcn_sched_barrier(0);
#pragma unroll
        for (int ks = 0; ks < 8; ++ks)  // wf5: 32 regs (col tile = wlo)
          wf5[ks] = *reinterpret_cast<const bf16x8*>(
              wb + OFF_W5 + (wlo * 16 + l15) * 256 + ks * 32 + quad * 8);
        bv5 = *reinterpret_cast<const f32x4*>(bws + 960 + wlo * 16 + quad * 4);
      }
      epi_pt2(accA, A32, 2);
      epi_pt2(accB, A32, 3);
      // pair 2
      mfma_pair2(accA, accB, wf4, afA, afB, bv4);
      read_af8(afA, B32, 6);
      read_af8(afB, B32, 7);
      epi_pt2(accA, A32, 4);
      epi_pt2(accB, A32, 5);
      // pair 3
      mfma_pair2(accA, accB, wf4, afA, afB, bv4);
      epi_pt2(accA, A32, 6);
      epi_pt2(accB, A32, 7);
    }
    lds_barrier();

    // ---------- L5: A32 -> global (wave: pts p0..p0+3, col tile wlo) ----------
    {
      float* out_base = out + (size_t)(c * 2 + bq) * 64 * kHW + hw0;
      const int o = wlo * 16 + quad * 4;
      bf16x8 afA[8], afB[8];
      read_af8(afA, A32, p0);
      read_af8(afB, A32, p0 + 1);
#pragma unroll
      for (int pp = 0; pp < 2; ++pp) {
        f32x4 accA = bv5, accB = bv5;
#pragma unroll
        for (int ks = 0; ks < 8; ++ks) {
          accA = mf(wf5[ks], afA[ks], accA);
          accB = mf(wf5[ks], afB[ks], accB);
        }
        if (pp == 0) { read_af8(afA, A32, p0 + 2); read_af8(afB, A32, p0 + 3); }
        const int ptA = p0 + pp * 2, ptB = p0 + pp * 2 + 1;
        float* dstA = out_base + (size_t)o * kHW + (ptA * 16 + l15);
        float* dstB = out_base + (size_t)o * kHW + (ptB * 16 + l15);
#pragma unroll
        for (int r = 0; r < 4; ++r) dstA[(size_t)r * kHW] = accA[r];
#pragma unroll
        for (int r = 0; r < 4; ++r) dstB[(size_t)r * kHW] = accB[r];
      }
    }
    // No extra barrier: next iteration's L0 writes Y (disjoint from A32 read
    // here), and its L1 X-writes are ordered by the post-L0 barrier.
  }
}

extern "C" void kernel_launch(void* const* d_in, const int* in_sizes, int n_in,
                              void* d_out, int out_size, void* d_ws, size_t ws_size,
                              hipStream_t stream) {
  const float* feat  = (const float*)d_in[0];
  const float* times = (const float*)d_in[1];
  const float* w0 = (const float*)d_in[2];
  const float* b0 = (const float*)d_in[3];
  const float* w1 = (const float*)d_in[4];
  const float* b1 = (const float*)d_in[5];
  const float* w2 = (const float*)d_in[6];
  const float* b2 = (const float*)d_in[7];
  const float* w3 = (const float*)d_in[8];
  const float* b3 = (const float*)d_in[9];
  const float* w4 = (const float*)d_in[10];
  const float* b4 = (const float*)d_in[11];
  const float* w5 = (const float*)d_in[12];
  const float* b5 = (const float*)d_in[13];
  u16*   wb  = (u16*)d_ws;
  float* bws = (float*)((char*)d_ws + (size_t)W_TOTAL * 2);
  float* out = (float*)d_out;

  convert_weights<<<(W_TOTAL + B_TOTAL) / 256, 256, 0, stream>>>(
      w0, w1, w2, w3, w4, w5, b0, b1, b2, b3, b4, b5, wb, bws);

  if (ws_size >= WS_NEED) {
    u16* featT = (u16*)((char*)d_ws + FEAT_BYTE_OFF);
    convert_feat<<<1920, 256, 0, stream>>>(feat, featT);
    siren_main<true><<<960, 512, 0, stream>>>(feat, times, wb, bws, featT, out);
  } else {
    siren_main<false><<<960, 512, 0, stream>>>(feat, times, wb, bws, wb, out);
  }
}

// Round 9
// 491.772 us; speedup vs baseline: 1.1065x; 1.1065x over previous
//
#include <hip/hip_runtime.h>
#include <hip/hip_bf16.h>

typedef __bf16 bf16_t;
typedef bf16_t bf16x8 __attribute__((ext_vector_type(8)));
typedef float f32x4 __attribute__((ext_vector_type(4)));
typedef unsigned short u16;
typedef unsigned int u32;

static constexpr int kHW = 192 * 320;          // 61440
static constexpr float kC = 4.77464829275686f; // 30 / (2*pi)

__device__ __forceinline__ u16 f2bf(float f) {
  u32 u = __float_as_uint(f);
  return (u16)((u + 0x7FFFu + ((u >> 16) & 1u)) >> 16);
}

__device__ __forceinline__ u32 pack2(float a, float b) {
  __hip_bfloat162 h = __float22bfloat162_rn(make_float2(a, b));
  union { __hip_bfloat162 h2; u32 u; } cv;
  cv.h2 = h;
  return cv.u;
}

// LDS-visibility-only barrier: leaves global loads (weight prefetch) in flight.
__device__ __forceinline__ void lds_barrier() {
  __asm__ volatile("s_waitcnt lgkmcnt(0)\n\ts_barrier" ::: "memory");
}

// ---- d_ws layout ----
static constexpr int OFF_W0 = 0;        // [64][64] (t-col folded to bias)
static constexpr int OFF_W1 = 4096;     // [64][64]
static constexpr int OFF_W2 = 8192;     // [256][64]
static constexpr int OFF_W3 = 24576;    // [256][256]
static constexpr int OFF_W4 = 90112;    // [256][256]
static constexpr int OFF_W5 = 155648;   // [64][256] (not scaled)
static constexpr int W_TOTAL = 172032;
static constexpr int B_TOTAL = 1024;
static constexpr size_t FEAT_BYTE_OFF = 348160;
static constexpr size_t WS_NEED = FEAT_BYTE_OFF + (size_t)1920 * 8192;

__global__ void convert_weights(const float* __restrict__ w0, const float* __restrict__ w1,
                                const float* __restrict__ w2, const float* __restrict__ w3,
                                const float* __restrict__ w4, const float* __restrict__ w5,
                                const float* __restrict__ b0, const float* __restrict__ b1,
                                const float* __restrict__ b2, const float* __restrict__ b3,
                                const float* __restrict__ b4, const float* __restrict__ b5,
                                u16* __restrict__ wb, float* __restrict__ bws) {
  int i = blockIdx.x * 256 + threadIdx.x;
  if (i < W_TOTAL) {
    float v, s = kC;
    if (i < OFF_W1)      { int o = i >> 6, k = i & 63; v = w0[o * 65 + k]; }
    else if (i < OFF_W2) { v = w1[i - OFF_W1]; }
    else if (i < OFF_W3) { v = w2[i - OFF_W2]; }
    else if (i < OFF_W4) { v = w3[i - OFF_W3]; }
    else if (i < OFF_W5) { v = w4[i - OFF_W4]; }
    else                 { v = w5[i - OFF_W5]; s = 1.0f; }
    wb[i] = f2bf(v * s);
  } else {
    int j = i - W_TOTAL;
    float v;
    if (j < 64)       v = kC * b0[j];
    else if (j < 128) v = kC * w0[(j - 64) * 65 + 64];
    else if (j < 192) v = kC * b1[j - 128];
    else if (j < 448) v = kC * b2[j - 192];
    else if (j < 704) v = kC * b3[j - 448];
    else if (j < 960) v = kC * b4[j - 704];
    else              v = b5[j - 960];
    bws[j] = v;
  }
}

// Pre-transpose feat into the swizzled bf16 image (the exact L0 A-frag layout).
__global__ void convert_feat(const float* __restrict__ feat, u16* __restrict__ featT) {
  const int chunk = blockIdx.x;
  const int bq  = chunk / 960;
  const int hw0 = (chunk % 960) * 64;
  const int tid = threadIdx.x;
  const int p   = tid & 63;
  const int gg  = tid >> 6;
  const float* fbase = feat + (size_t)bq * 64 * kHW + hw0 + p;
  u16* img = featT + (size_t)chunk * 4096;
#pragma unroll
  for (int j = 0; j < 2; ++j) {
    const int g = gg * 2 + j;
    float v[8];
#pragma unroll
    for (int e = 0; e < 8; ++e) v[e] = fbase[(size_t)(g * 8 + e) * kHW];
    uint4 pk;
    pk.x = pack2(v[0], v[1]);
    pk.y = pack2(v[2], v[3]);
    pk.z = pack2(v[4], v[5]);
    pk.w = pack2(v[6], v[7]);
    *reinterpret_cast<uint4*>(img + p * 64 + ((g ^ (p & 7)) * 8)) = pk;
  }
}

template<int RSO>
__device__ __forceinline__ void epilogue_sin(f32x4 acc, u16* outb, int p, int g,
                                             int quad, int sw) {
  float s0 = __builtin_amdgcn_sinf(__builtin_amdgcn_fractf(acc[0]));
  float s1 = __builtin_amdgcn_sinf(__builtin_amdgcn_fractf(acc[1]));
  float s2 = __builtin_amdgcn_sinf(__builtin_amdgcn_fractf(acc[2]));
  float s3 = __builtin_amdgcn_sinf(__builtin_amdgcn_fractf(acc[3]));
  uint2 v;
  v.x = pack2(s0, s1);
  v.y = pack2(s2, s3);
  *reinterpret_cast<uint2*>(outb + p * RSO + ((g ^ sw) * 8) + (quad & 1) * 4) = v;
}

__device__ __forceinline__ f32x4 mf(bf16x8 a, bf16x8 b, f32x4 c) {
  return __builtin_amdgcn_mfma_f32_16x16x32_bf16(a, b, c, 0, 0, 0);
}

// R9: R7 structure + in-block c-loop (grid 960). UNLIKE R8 (which spilled:
// FETCH 632GB/WRITE 685GB scale), wf3/wf4/wf5 are RELOADED every c so per-c
// register lifetimes are exactly R7's (wf3 dies after L3, wf4 after L4; no
// persistence). Only wf0/1/2 + biases (~48 regs) persist. Gains: 2 fewer
// block restarts per CU-slot; L5(c) overlaps L0(c+1) (L5 reads A32, L0
// writes Y — disjoint; L1's X-writes ordered by the post-L0 barrier).
// Weight reloads per c hit L2-hot lines (same traffic R7 paid).
template<bool PRE>
__global__ __attribute__((amdgpu_waves_per_eu(2, 2)))
void __launch_bounds__(512)
siren_main(const float* __restrict__ feat, const float* __restrict__ times,
           const u16* __restrict__ wb, const float* __restrict__ bws,
           const u16* __restrict__ featT, float* __restrict__ out) {
  __shared__ __align__(16) u16 A32[128 * 256];   // 64 KB
  __shared__ __align__(16) u16 B32[128 * 256];   // 64 KB
  u16* X = B32;          // 128x64 compact (stride 64), aliases B32 (dead by L3)
  u16* Y = B32 + 8192;

  const int tid   = threadIdx.x;
  const int pair  = blockIdx.x;    // 0..959: covers old chunks 2*pair, 2*pair+1
  const int bq    = pair / 480;
  const int hw0   = (pair % 480) * 128;
  const int wave  = tid >> 6;      // 0..7
  const int lane  = tid & 63;
  const int l15   = lane & 15;
  const int quad  = lane >> 4;
  const int sw    = l15 & 7;
  const int wlo   = wave & 3;      // col tile for 64-wide layers / L5
  const int p0    = (wave >> 2) * 4; // 64-wide layers / L5: pts p0..p0+3

  // ---------- helpers ----------
  auto read_af8 = [&](bf16x8 (&af)[8], const u16* in, int pt) {
#pragma unroll
    for (int ks = 0; ks < 8; ++ks)
      af[ks] = *reinterpret_cast<const bf16x8*>(
          in + (pt * 16 + l15) * 256 + (((ks * 4 + quad) ^ sw) * 8));
  };
  auto read_af2 = [&](bf16x8 (&af)[2], const u16* in, int pt) {
#pragma unroll
    for (int ks = 0; ks < 2; ++ks)
      af[ks] = *reinterpret_cast<const bf16x8*>(
          in + (pt * 16 + l15) * 64 + (((ks * 4 + quad) ^ sw) * 8));
  };
  // Full 256-wide weight fragment for this wave's 32 rows: 16 bf16x8 = 64 regs.
  auto load_wf16 = [&](bf16x8 (&wf)[2][8], const u16* wbase) {
#pragma unroll
    for (int ot = 0; ot < 2; ++ot)
#pragma unroll
      for (int ks = 0; ks < 8; ++ks)
        wf[ot][ks] = *reinterpret_cast<const bf16x8*>(
            wbase + ((wave * 2 + ot) * 16 + l15) * 256 + ks * 32 + quad * 8);
  };
  auto load_bv2 = [&](f32x4 (&bv)[2], const float* bg) {
#pragma unroll
    for (int ot = 0; ot < 2; ++ot)
      bv[ot] = *reinterpret_cast<const f32x4*>(bg + (wave * 2 + ot) * 16 + quad * 4);
  };
  // Two pt-tiles interleaved: 4 independent chains (2 ot x 2 pt).
  auto mfma_pair2 = [&](f32x4 (&accA)[2], f32x4 (&accB)[2], bf16x8 (&wf)[2][8],
                        bf16x8 (&afA)[8], bf16x8 (&afB)[8], const f32x4 (&bv)[2]) {
#pragma unroll
    for (int ot = 0; ot < 2; ++ot) { accA[ot] = bv[ot]; accB[ot] = bv[ot]; }
#pragma unroll
    for (int ks = 0; ks < 8; ++ks)
#pragma unroll
      for (int ot = 0; ot < 2; ++ot) {
        accA[ot] = mf(wf[ot][ks], afA[ks], accA[ot]);
        accB[ot] = mf(wf[ot][ks], afB[ks], accB[ot]);
      }
  };
  auto epi_pt2 = [&](f32x4 (&acc)[2], u16* outb, int pt) {
#pragma unroll
    for (int ot = 0; ot < 2; ++ot)
      epilogue_sin<256>(acc[ot], outb, pt * 16 + l15,
                        (wave * 2 + ot) * 2 + (quad >> 1), quad, sw);
  };

  // ---------- small persistent weights (48 regs): wf0, wf1, wf2, biases ----------
  bf16x8 wf0[2], wf1[2];
  bf16x8 wf2[2][2];
  f32x4  cb, cw, bv1, bv2[2];
#pragma unroll
  for (int ks = 0; ks < 2; ++ks) {
    wf0[ks] = *reinterpret_cast<const bf16x8*>(wb + OFF_W0 + (wlo * 16 + l15) * 64 + ks * 32 + quad * 8);
    wf1[ks] = *reinterpret_cast<const bf16x8*>(wb + OFF_W1 + (wlo * 16 + l15) * 64 + ks * 32 + quad * 8);
  }
#pragma unroll
  for (int ot = 0; ot < 2; ++ot)
#pragma unroll
    for (int ks = 0; ks < 2; ++ks)
      wf2[ot][ks] = *reinterpret_cast<const bf16x8*>(
          wb + OFF_W2 + ((wave * 2 + ot) * 16 + l15) * 64 + ks * 32 + quad * 8);
  cb  = *reinterpret_cast<const f32x4*>(bws + wlo * 16 + quad * 4);
  cw  = *reinterpret_cast<const f32x4*>(bws + 64 + wlo * 16 + quad * 4);
  bv1 = *reinterpret_cast<const f32x4*>(bws + 128 + wlo * 16 + quad * 4);
  load_bv2(bv2, bws + 192);

  for (int c = 0; c < 3; ++c) {
    const float t = times[c];
    f32x4 bv0;
#pragma unroll
    for (int r = 0; r < 4; ++r) bv0[r] = cb[r] + t * cw[r];

    // ---------- L0: featT(global) or X(LDS) -> Y (wave: pts p0..p0+3, col wlo) ----------
    if constexpr (PRE) {
      const u16* fsrc = featT + (size_t)pair * 8192;
      bf16x8 a[4][2];
#pragma unroll
      for (int p = 0; p < 4; ++p)
#pragma unroll
        for (int ks = 0; ks < 2; ++ks)
          a[p][ks] = *reinterpret_cast<const bf16x8*>(
              fsrc + ((p0 + p) * 16 + l15) * 64 + (((ks * 4 + quad) ^ sw) * 8));
      f32x4 accp[4];
#pragma unroll
      for (int p = 0; p < 4; ++p) accp[p] = bv0;
#pragma unroll
      for (int ks = 0; ks < 2; ++ks)
#pragma unroll
        for (int p = 0; p < 4; ++p) accp[p] = mf(wf0[ks], a[p][ks], accp[p]);
#pragma unroll
      for (int p = 0; p < 4; ++p)
        epilogue_sin<64>(accp[p], Y, (p0 + p) * 16 + l15, wlo * 2 + (quad >> 1), quad, sw);
    } else {
      // fallback: stage 128px into X, then classic LDS path (restaged per c)
      {
        const int p  = tid & 127;    // 0..127
        const int gg = tid >> 7;     // 0..3
        const float* fbase = feat + (size_t)bq * 64 * kHW + hw0 + p;
#pragma unroll
        for (int j = 0; j < 2; ++j) {
          const int g = gg * 2 + j;
          float v[8];
#pragma unroll
          for (int e = 0; e < 8; ++e) v[e] = fbase[(size_t)(g * 8 + e) * kHW];
          uint4 pk;
          pk.x = pack2(v[0], v[1]);
          pk.y = pack2(v[2], v[3]);
          pk.z = pack2(v[4], v[5]);
          pk.w = pack2(v[6], v[7]);
          *reinterpret_cast<uint4*>(X + p * 64 + ((g ^ (p & 7)) * 8)) = pk;
        }
      }
      lds_barrier();
#pragma unroll
      for (int p = 0; p < 4; ++p) {
        bf16x8 a[2];
        read_af2(a, X, p0 + p);
        f32x4 acc = bv0;
        acc = mf(wf0[0], a[0], acc); acc = mf(wf0[1], a[1], acc);
        epilogue_sin<64>(acc, Y, (p0 + p) * 16 + l15, wlo * 2 + (quad >> 1), quad, sw);
      }
    }
    lds_barrier();

    // ---------- L1: Y -> X ; issue FULL wf3 here each c (window = L1+L2) ----------
    bf16x8 wf3[2][8];
    f32x4  bv3[2];
    {
      bf16x8 a[4][2];
      read_af2(a[0], Y, p0);
      read_af2(a[1], Y, p0 + 1);
      read_af2(a[2], Y, p0 + 2);
      read_af2(a[3], Y, p0 + 3);
      load_wf16(wf3, wb + OFF_W3);
      load_bv2(bv3, bws + 448);
      f32x4 accp[4];
#pragma unroll
      for (int p = 0; p < 4; ++p) accp[p] = bv1;
#pragma unroll
      for (int ks = 0; ks < 2; ++ks)
#pragma unroll
        for (int p = 0; p < 4; ++p) accp[p] = mf(wf1[ks], a[p][ks], accp[p]);
#pragma unroll
      for (int p = 0; p < 4; ++p)
        epilogue_sin<64>(accp[p], X, (p0 + p) * 16 + l15, wlo * 2 + (quad >> 1), quad, sw);
    }
    lds_barrier();

    // ---------- L2: X -> A32 (all 8 pts per wave, 2 out tiles) ----------
    {
      bf16x8 aA[2], aB[2];
      read_af2(aA, X, 0);
      read_af2(aB, X, 1);
      f32x4 accA[2], accB[2];
#pragma unroll
      for (int pp = 0; pp < 4; ++pp) {
#pragma unroll
        for (int ot = 0; ot < 2; ++ot) { accA[ot] = bv2[ot]; accB[ot] = bv2[ot]; }
#pragma unroll
        for (int ks = 0; ks < 2; ++ks)
#pragma unroll
          for (int ot = 0; ot < 2; ++ot) {
            accA[ot] = mf(wf2[ot][ks], aA[ks], accA[ot]);
            accB[ot] = mf(wf2[ot][ks], aB[ks], accB[ot]);
          }
        if (pp < 3) {
          read_af2(aA, X, pp * 2 + 2);
          read_af2(aB, X, pp * 2 + 3);
        }
        epi_pt2(accA, A32, pp * 2);
        epi_pt2(accB, A32, pp * 2 + 1);
      }
    }
    lds_barrier();

    // ---------- L3: A32 -> B32 ; mid-issue FULL wf4 each c ----------
    bf16x8 wf4[2][8];
    f32x4  bv4[2];
    {
      bf16x8 afA[8], afB[8];
      f32x4 accA[2], accB[2];
      read_af8(afA, A32, 0);
      read_af8(afB, A32, 1);
      // pair 0
      mfma_pair2(accA, accB, wf3, afA, afB, bv3);
      read_af8(afA, A32, 2);
      read_af8(afB, A32, 3);
      epi_pt2(accA, B32, 0);
      epi_pt2(accB, B32, 1);
      // pair 1
      mfma_pair2(accA, accB, wf3, afA, afB, bv3);
      read_af8(afA, A32, 4);
      read_af8(afB, A32, 5);
      // wf4 full prefetch: pinned so it can't hoist above pair-0/1 (reg peak).
      __builtin_amdgcn_sched_barrier(0);
      load_wf16(wf4, wb + OFF_W4);
      load_bv2(bv4, bws + 704);
      epi_pt2(accA, B32, 2);
      epi_pt2(accB, B32, 3);
      // pair 2
      mfma_pair2(accA, accB, wf3, afA, afB, bv3);
      read_af8(afA, A32, 6);
      read_af8(afB, A32, 7);
      epi_pt2(accA, B32, 4);
      epi_pt2(accB, B32, 5);
      // pair 3
      mfma_pair2(accA, accB, wf3, afA, afB, bv3);
      epi_pt2(accA, B32, 6);
      epi_pt2(accB, B32, 7);
    }
    lds_barrier();

    // ---------- L4: B32 -> A32 ; mid-issue wf5 each c (32 regs) ----------
    bf16x8 wf5[8];
    f32x4  bv5;
    {
      bf16x8 afA[8], afB[8];
      f32x4 accA[2], accB[2];
      read_af8(afA, B32, 0);
      read_af8(afB, B32, 1);
      // pair 0
      mfma_pair2(accA, accB, wf4, afA, afB, bv4);
      read_af8(afA, B32, 2);
      read_af8(afB, B32, 3);
      epi_pt2(accA, A32, 0);
      epi_pt2(accB, A32, 1);
      // pair 1
      mfma_pair2(accA, accB, wf4, afA, afB, bv4);
      read_af8(afA, B32, 4);
      read_af8(afB, B32, 5);
      __builtin_amdgcn_sched_barrier(0);
#pragma unroll
      for (int ks = 0; ks < 8; ++ks)  // wf5: 32 regs (col tile = wlo)
        wf5[ks] = *reinterpret_cast<const bf16x8*>(
            wb + OFF_W5 + (wlo * 16 + l15) * 256 + ks * 32 + quad * 8);
      bv5 = *reinterpret_cast<const f32x4*>(bws + 960 + wlo * 16 + quad * 4);
      epi_pt2(accA, A32, 2);
      epi_pt2(accB, A32, 3);
      // pair 2
      mfma_pair2(accA, accB, wf4, afA, afB, bv4);
      read_af8(afA, B32, 6);
      read_af8(afB, B32, 7);
      epi_pt2(accA, A32, 4);
      epi_pt2(accB, A32, 5);
      // pair 3
      mfma_pair2(accA, accB, wf4, afA, afB, bv4);
      epi_pt2(accA, A32, 6);
      epi_pt2(accB, A32, 7);
    }
    lds_barrier();

    // ---------- L5: A32 -> global (wave: pts p0..p0+3, col tile wlo) ----------
    {
      float* out_base = out + (size_t)(c * 2 + bq) * 64 * kHW + hw0;
      const int o = wlo * 16 + quad * 4;
      bf16x8 afA[8], afB[8];
      read_af8(afA, A32, p0);
      read_af8(afB, A32, p0 + 1);
#pragma unroll
      for (int pp = 0; pp < 2; ++pp) {
        f32x4 accA = bv5, accB = bv5;
#pragma unroll
        for (int ks = 0; ks < 8; ++ks) {
          accA = mf(wf5[ks], afA[ks], accA);
          accB = mf(wf5[ks], afB[ks], accB);
        }
        if (pp == 0) { read_af8(afA, A32, p0 + 2); read_af8(afB, A32, p0 + 3); }
        const int ptA = p0 + pp * 2, ptB = p0 + pp * 2 + 1;
        float* dstA = out_base + (size_t)o * kHW + (ptA * 16 + l15);
        float* dstB = out_base + (size_t)o * kHW + (ptB * 16 + l15);
#pragma unroll
        for (int r = 0; r < 4; ++r) dstA[(size_t)r * kHW] = accA[r];
#pragma unroll
        for (int r = 0; r < 4; ++r) dstB[(size_t)r * kHW] = accB[r];
      }
    }
    // No barrier here: next c's L0 writes Y (disjoint from A32 read by L5),
    // and its L1 X-writes are ordered by the post-L0 barrier.
  }
}

extern "C" void kernel_launch(void* const* d_in, const int* in_sizes, int n_in,
                              void* d_out, int out_size, void* d_ws, size_t ws_size,
                              hipStream_t stream) {
  const float* feat  = (const float*)d_in[0];
  const float* times = (const float*)d_in[1];
  const float* w0 = (const float*)d_in[2];
  const float* b0 = (const float*)d_in[3];
  const float* w1 = (const float*)d_in[4];
  const float* b1 = (const float*)d_in[5];
  const float* w2 = (const float*)d_in[6];
  const float* b2 = (const float*)d_in[7];
  const float* w3 = (const float*)d_in[8];
  const float* b3 = (const float*)d_in[9];
  const float* w4 = (const float*)d_in[10];
  const float* b4 = (const float*)d_in[11];
  const float* w5 = (const float*)d_in[12];
  const float* b5 = (const float*)d_in[13];
  u16*   wb  = (u16*)d_ws;
  float* bws = (float*)((char*)d_ws + (size_t)W_TOTAL * 2);
  float* out = (float*)d_out;

  convert_weights<<<(W_TOTAL + B_TOTAL) / 256, 256, 0, stream>>>(
      w0, w1, w2, w3, w4, w5, b0, b1, b2, b3, b4, b5, wb, bws);

  if (ws_size >= WS_NEED) {
    u16* featT = (u16*)((char*)d_ws + FEAT_BYTE_OFF);
    convert_feat<<<1920, 256, 0, stream>>>(feat, featT);
    siren_main<true><<<960, 512, 0, stream>>>(feat, times, wb, bws, featT, out);
  } else {
    siren_main<false><<<960, 512, 0, stream>>>(feat, times, wb, bws, wb, out);
  }
}

// Round 10
// 337.252 us; speedup vs baseline: 1.6134x; 1.4582x over previous
//
#include <hip/hip_runtime.h>
#include <hip/hip_bf16.h>

typedef __bf16 bf16_t;
typedef bf16_t bf16x8 __attribute__((ext_vector_type(8)));
typedef float f32x4 __attribute__((ext_vector_type(4)));
typedef unsigned short u16;
typedef unsigned int u32;

static constexpr int kHW = 192 * 320;          // 61440
static constexpr float kC = 4.77464829275686f; // 30 / (2*pi)

__device__ __forceinline__ u16 f2bf(float f) {
  u32 u = __float_as_uint(f);
  return (u16)((u + 0x7FFFu + ((u >> 16) & 1u)) >> 16);
}

__device__ __forceinline__ u32 pack2(float a, float b) {
  __hip_bfloat162 h = __float22bfloat162_rn(make_float2(a, b));
  union { __hip_bfloat162 h2; u32 u; } cv;
  cv.h2 = h;
  return cv.u;
}

// LDS-visibility-only barrier: leaves global loads (weight prefetch) in flight.
__device__ __forceinline__ void lds_barrier() {
  __asm__ volatile("s_waitcnt lgkmcnt(0)\n\ts_barrier" ::: "memory");
}

// ---- d_ws layout ----
static constexpr int OFF_W0 = 0;        // [64][64] (t-col folded to bias)
static constexpr int OFF_W1 = 4096;     // [64][64]
static constexpr int OFF_W2 = 8192;     // [256][64]
static constexpr int OFF_W3 = 24576;    // [256][256]
static constexpr int OFF_W4 = 90112;    // [256][256]
static constexpr int OFF_W5 = 155648;   // [64][256] (not scaled)
static constexpr int W_TOTAL = 172032;
static constexpr int B_TOTAL = 1024;
static constexpr size_t FEAT_BYTE_OFF = 348160;
static constexpr size_t WS_NEED = FEAT_BYTE_OFF + (size_t)1920 * 8192;

__global__ void convert_weights(const float* __restrict__ w0, const float* __restrict__ w1,
                                const float* __restrict__ w2, const float* __restrict__ w3,
                                const float* __restrict__ w4, const float* __restrict__ w5,
                                const float* __restrict__ b0, const float* __restrict__ b1,
                                const float* __restrict__ b2, const float* __restrict__ b3,
                                const float* __restrict__ b4, const float* __restrict__ b5,
                                u16* __restrict__ wb, float* __restrict__ bws) {
  int i = blockIdx.x * 256 + threadIdx.x;
  if (i < W_TOTAL) {
    float v, s = kC;
    if (i < OFF_W1)      { int o = i >> 6, k = i & 63; v = w0[o * 65 + k]; }
    else if (i < OFF_W2) { v = w1[i - OFF_W1]; }
    else if (i < OFF_W3) { v = w2[i - OFF_W2]; }
    else if (i < OFF_W4) { v = w3[i - OFF_W3]; }
    else if (i < OFF_W5) { v = w4[i - OFF_W4]; }
    else                 { v = w5[i - OFF_W5]; s = 1.0f; }
    wb[i] = f2bf(v * s);
  } else {
    int j = i - W_TOTAL;
    float v;
    if (j < 64)       v = kC * b0[j];
    else if (j < 128) v = kC * w0[(j - 64) * 65 + 64];
    else if (j < 192) v = kC * b1[j - 128];
    else if (j < 448) v = kC * b2[j - 192];
    else if (j < 704) v = kC * b3[j - 448];
    else if (j < 960) v = kC * b4[j - 704];
    else              v = b5[j - 960];
    bws[j] = v;
  }
}

// Pre-transpose feat into the swizzled bf16 image (the exact L0 A-frag layout).
__global__ void convert_feat(const float* __restrict__ feat, u16* __restrict__ featT) {
  const int chunk = blockIdx.x;
  const int bq  = chunk / 960;
  const int hw0 = (chunk % 960) * 64;
  const int tid = threadIdx.x;
  const int p   = tid & 63;
  const int gg  = tid >> 6;
  const float* fbase = feat + (size_t)bq * 64 * kHW + hw0 + p;
  u16* img = featT + (size_t)chunk * 4096;
#pragma unroll
  for (int j = 0; j < 2; ++j) {
    const int g = gg * 2 + j;
    float v[8];
#pragma unroll
    for (int e = 0; e < 8; ++e) v[e] = fbase[(size_t)(g * 8 + e) * kHW];
    uint4 pk;
    pk.x = pack2(v[0], v[1]);
    pk.y = pack2(v[2], v[3]);
    pk.z = pack2(v[4], v[5]);
    pk.w = pack2(v[6], v[7]);
    *reinterpret_cast<uint4*>(img + p * 64 + ((g ^ (p & 7)) * 8)) = pk;
  }
}

template<int RSO>
__device__ __forceinline__ void epilogue_sin(f32x4 acc, u16* outb, int p, int g,
                                             int quad, int sw) {
  float s0 = __builtin_amdgcn_sinf(__builtin_amdgcn_fractf(acc[0]));
  float s1 = __builtin_amdgcn_sinf(__builtin_amdgcn_fractf(acc[1]));
  float s2 = __builtin_amdgcn_sinf(__builtin_amdgcn_fractf(acc[2]));
  float s3 = __builtin_amdgcn_sinf(__builtin_amdgcn_fractf(acc[3]));
  uint2 v;
  v.x = pack2(s0, s1);
  v.y = pack2(s2, s3);
  *reinterpret_cast<uint2*>(outb + p * RSO + ((g ^ sw) * 8) + (quad & 1) * 4) = v;
}

__device__ __forceinline__ f32x4 mf(bf16x8 a, bf16x8 b, f32x4 c) {
  return __builtin_amdgcn_mfma_f32_16x16x32_bf16(a, b, c, 0, 0, 0);
}

// R10 = R7 (proven best: 227 µs, no spill). 128-px blocks (512 threads,
// 8 waves, 128KB LDS, 1 block/CU, 2 waves/SIMD). Each wave owns 32 out-rows
// of the 256-wide layers -> weight frags 64 regs; full next-layer weights
// prefetch mid-layer. R8/R9 (c-fusion with persistent weights) both spilled:
// L3's peak (wf3+wf4+af+acc ~210) leaves <50 spare regs — NOTHING may live
// across L3. Do not add persistent state to this kernel.
template<bool PRE>
__global__ __attribute__((amdgpu_waves_per_eu(2, 2)))
void __launch_bounds__(512)
siren_main(const float* __restrict__ feat, const float* __restrict__ times,
           const u16* __restrict__ wb, const float* __restrict__ bws,
           const u16* __restrict__ featT, float* __restrict__ out) {
  __shared__ __align__(16) u16 A32[128 * 256];   // 64 KB
  __shared__ __align__(16) u16 B32[128 * 256];   // 64 KB
  u16* X = B32;          // 128x64 compact (stride 64), aliases B32 (dead by L3)
  u16* Y = B32 + 8192;

  const int tid   = threadIdx.x;
  const int bid   = blockIdx.x;
  const int c     = bid / 960;
  const int pair  = bid % 960;     // covers old chunks 2*pair, 2*pair+1
  const int bq    = pair / 480;
  const int hw0   = (pair % 480) * 128;
  const float t   = times[c];
  const int wave  = tid >> 6;      // 0..7
  const int lane  = tid & 63;
  const int l15   = lane & 15;
  const int quad  = lane >> 4;
  const int sw    = l15 & 7;
  const int wlo   = wave & 3;      // col tile for 64-wide layers / L5
  const int p0    = (wave >> 2) * 4; // 64-wide layers / L5: pts p0..p0+3

  // ---------- helpers ----------
  auto read_af8 = [&](bf16x8 (&af)[8], const u16* in, int pt) {
#pragma unroll
    for (int ks = 0; ks < 8; ++ks)
      af[ks] = *reinterpret_cast<const bf16x8*>(
          in + (pt * 16 + l15) * 256 + (((ks * 4 + quad) ^ sw) * 8));
  };
  auto read_af2 = [&](bf16x8 (&af)[2], const u16* in, int pt) {
#pragma unroll
    for (int ks = 0; ks < 2; ++ks)
      af[ks] = *reinterpret_cast<const bf16x8*>(
          in + (pt * 16 + l15) * 64 + (((ks * 4 + quad) ^ sw) * 8));
  };
  // Full 256-wide weight fragment for this wave's 32 rows: 16 bf16x8 = 64 regs.
  auto load_wf16 = [&](bf16x8 (&wf)[2][8], const u16* wbase) {
#pragma unroll
    for (int ot = 0; ot < 2; ++ot)
#pragma unroll
      for (int ks = 0; ks < 8; ++ks)
        wf[ot][ks] = *reinterpret_cast<const bf16x8*>(
            wbase + ((wave * 2 + ot) * 16 + l15) * 256 + ks * 32 + quad * 8);
  };
  auto load_bv2 = [&](f32x4 (&bv)[2], const float* bg) {
#pragma unroll
    for (int ot = 0; ot < 2; ++ot)
      bv[ot] = *reinterpret_cast<const f32x4*>(bg + (wave * 2 + ot) * 16 + quad * 4);
  };
  // Two pt-tiles interleaved: 4 independent chains (2 ot x 2 pt).
  auto mfma_pair2 = [&](f32x4 (&accA)[2], f32x4 (&accB)[2], bf16x8 (&wf)[2][8],
                        bf16x8 (&afA)[8], bf16x8 (&afB)[8], const f32x4 (&bv)[2]) {
#pragma unroll
    for (int ot = 0; ot < 2; ++ot) { accA[ot] = bv[ot]; accB[ot] = bv[ot]; }
#pragma unroll
    for (int ks = 0; ks < 8; ++ks)
#pragma unroll
      for (int ot = 0; ot < 2; ++ot) {
        accA[ot] = mf(wf[ot][ks], afA[ks], accA[ot]);
        accB[ot] = mf(wf[ot][ks], afB[ks], accB[ot]);
      }
  };
  auto epi_pt2 = [&](f32x4 (&acc)[2], u16* outb, int pt) {
#pragma unroll
    for (int ot = 0; ot < 2; ++ot)
      epilogue_sin<256>(acc[ot], outb, pt * 16 + l15,
                        (wave * 2 + ot) * 2 + (quad >> 1), quad, sw);
  };

  // ---------- preload L0/L1 weights + biases (col tile = wlo) ----------
  bf16x8 wf0[2], wf1[2];
#pragma unroll
  for (int ks = 0; ks < 2; ++ks) {
    wf0[ks] = *reinterpret_cast<const bf16x8*>(wb + OFF_W0 + (wlo * 16 + l15) * 64 + ks * 32 + quad * 8);
    wf1[ks] = *reinterpret_cast<const bf16x8*>(wb + OFF_W1 + (wlo * 16 + l15) * 64 + ks * 32 + quad * 8);
  }
  f32x4 bv0, bv1;
  {
    f32x4 cb = *reinterpret_cast<const f32x4*>(bws + wlo * 16 + quad * 4);
    f32x4 cw = *reinterpret_cast<const f32x4*>(bws + 64 + wlo * 16 + quad * 4);
#pragma unroll
    for (int r = 0; r < 4; ++r) bv0[r] = cb[r] + t * cw[r];
    bv1 = *reinterpret_cast<const f32x4*>(bws + 128 + wlo * 16 + quad * 4);
  }

  bf16x8 wf2[2][2];
  f32x4  bv2[2];

  // ---------- L0: featT(global) or X(LDS) -> Y (wave: pts p0..p0+3, col wlo) ----------
  if constexpr (PRE) {
    const u16* fsrc = featT + (size_t)pair * 8192;
    bf16x8 a[4][2];
#pragma unroll
    for (int p = 0; p < 4; ++p)
#pragma unroll
      for (int ks = 0; ks < 2; ++ks)
        a[p][ks] = *reinterpret_cast<const bf16x8*>(
            fsrc + ((p0 + p) * 16 + l15) * 64 + (((ks * 4 + quad) ^ sw) * 8));
    // L2-layer weights: issue now, consumed two layers later (8 regs)
#pragma unroll
    for (int ot = 0; ot < 2; ++ot)
#pragma unroll
      for (int ks = 0; ks < 2; ++ks)
        wf2[ot][ks] = *reinterpret_cast<const bf16x8*>(
            wb + OFF_W2 + ((wave * 2 + ot) * 16 + l15) * 64 + ks * 32 + quad * 8);
    load_bv2(bv2, bws + 192);

    f32x4 accp[4];
#pragma unroll
    for (int p = 0; p < 4; ++p) accp[p] = bv0;
#pragma unroll
    for (int ks = 0; ks < 2; ++ks)
#pragma unroll
      for (int p = 0; p < 4; ++p) accp[p] = mf(wf0[ks], a[p][ks], accp[p]);
#pragma unroll
    for (int p = 0; p < 4; ++p)
      epilogue_sin<64>(accp[p], Y, (p0 + p) * 16 + l15, wlo * 2 + (quad >> 1), quad, sw);
  } else {
    // fallback: stage 128px into X, then classic LDS path
    {
      const int p  = tid & 127;    // 0..127
      const int gg = tid >> 7;     // 0..3
      const float* fbase = feat + (size_t)bq * 64 * kHW + hw0 + p;
#pragma unroll
      for (int j = 0; j < 2; ++j) {
        const int g = gg * 2 + j;
        float v[8];
#pragma unroll
        for (int e = 0; e < 8; ++e) v[e] = fbase[(size_t)(g * 8 + e) * kHW];
        uint4 pk;
        pk.x = pack2(v[0], v[1]);
        pk.y = pack2(v[2], v[3]);
        pk.z = pack2(v[4], v[5]);
        pk.w = pack2(v[6], v[7]);
        *reinterpret_cast<uint4*>(X + p * 64 + ((g ^ (p & 7)) * 8)) = pk;
      }
    }
    lds_barrier();
#pragma unroll
    for (int ot = 0; ot < 2; ++ot)
#pragma unroll
      for (int ks = 0; ks < 2; ++ks)
        wf2[ot][ks] = *reinterpret_cast<const bf16x8*>(
            wb + OFF_W2 + ((wave * 2 + ot) * 16 + l15) * 64 + ks * 32 + quad * 8);
    load_bv2(bv2, bws + 192);
#pragma unroll
    for (int p = 0; p < 4; ++p) {
      bf16x8 a[2];
      read_af2(a, X, p0 + p);
      f32x4 acc = bv0;
      acc = mf(wf0[0], a[0], acc); acc = mf(wf0[1], a[1], acc);
      epilogue_sin<64>(acc, Y, (p0 + p) * 16 + l15, wlo * 2 + (quad >> 1), quad, sw);
    }
  }
  lds_barrier();

  // ---------- L1: Y -> X ; issue FULL wf3 here (64 regs, window = L1+L2) ----------
  bf16x8 wf3[2][8];
  f32x4  bv3[2];
  {
    bf16x8 a[4][2];
    read_af2(a[0], Y, p0);
    read_af2(a[1], Y, p0 + 1);
    read_af2(a[2], Y, p0 + 2);
    read_af2(a[3], Y, p0 + 3);
    load_wf16(wf3, wb + OFF_W3);
    load_bv2(bv3, bws + 448);
    f32x4 accp[4];
#pragma unroll
    for (int p = 0; p < 4; ++p) accp[p] = bv1;
#pragma unroll
    for (int ks = 0; ks < 2; ++ks)
#pragma unroll
      for (int p = 0; p < 4; ++p) accp[p] = mf(wf1[ks], a[p][ks], accp[p]);
#pragma unroll
    for (int p = 0; p < 4; ++p)
      epilogue_sin<64>(accp[p], X, (p0 + p) * 16 + l15, wlo * 2 + (quad >> 1), quad, sw);
  }
  lds_barrier();

  // ---------- L2: X -> A32 (all 8 pts per wave, 2 out tiles) ----------
  {
    bf16x8 aA[2], aB[2];
    read_af2(aA, X, 0);
    read_af2(aB, X, 1);
    f32x4 accA[2], accB[2];
#pragma unroll
    for (int pp = 0; pp < 4; ++pp) {
#pragma unroll
      for (int ot = 0; ot < 2; ++ot) { accA[ot] = bv2[ot]; accB[ot] = bv2[ot]; }
#pragma unroll
      for (int ks = 0; ks < 2; ++ks)
#pragma unroll
        for (int ot = 0; ot < 2; ++ot) {
          accA[ot] = mf(wf2[ot][ks], aA[ks], accA[ot]);
          accB[ot] = mf(wf2[ot][ks], aB[ks], accB[ot]);
        }
      if (pp < 3) {
        read_af2(aA, X, pp * 2 + 2);
        read_af2(aB, X, pp * 2 + 3);
      }
      epi_pt2(accA, A32, pp * 2);
      epi_pt2(accB, A32, pp * 2 + 1);
    }
  }
  lds_barrier();

  // ---------- L3: A32 -> B32 ; mid-issue FULL wf4 (peak ~244 regs) ----------
  bf16x8 wf4[2][8];
  f32x4  bv4[2];
  {
    bf16x8 afA[8], afB[8];
    f32x4 accA[2], accB[2];
    read_af8(afA, A32, 0);
    read_af8(afB, A32, 1);
    // pair 0
    mfma_pair2(accA, accB, wf3, afA, afB, bv3);
    read_af8(afA, A32, 2);
    read_af8(afB, A32, 3);
    epi_pt2(accA, B32, 0);
    epi_pt2(accB, B32, 1);
    // pair 1
    mfma_pair2(accA, accB, wf3, afA, afB, bv3);
    read_af8(afA, A32, 4);
    read_af8(afB, A32, 5);
    // wf4 full prefetch: pinned so it can't hoist above pair-0/1 (reg peak).
    __builtin_amdgcn_sched_barrier(0);
    load_wf16(wf4, wb + OFF_W4);
    load_bv2(bv4, bws + 704);
    epi_pt2(accA, B32, 2);
    epi_pt2(accB, B32, 3);
    // pair 2
    mfma_pair2(accA, accB, wf3, afA, afB, bv3);
    read_af8(afA, A32, 6);
    read_af8(afB, A32, 7);
    epi_pt2(accA, B32, 4);
    epi_pt2(accB, B32, 5);
    // pair 3
    mfma_pair2(accA, accB, wf3, afA, afB, bv3);
    epi_pt2(accA, B32, 6);
    epi_pt2(accB, B32, 7);
  }
  lds_barrier();

  // ---------- L4: B32 -> A32 ; mid-issue wf5 (32 regs) ----------
  bf16x8 wf5[8];
  f32x4  bv5;
  {
    bf16x8 afA[8], afB[8];
    f32x4 accA[2], accB[2];
    read_af8(afA, B32, 0);
    read_af8(afB, B32, 1);
    // pair 0
    mfma_pair2(accA, accB, wf4, afA, afB, bv4);
    read_af8(afA, B32, 2);
    read_af8(afB, B32, 3);
    epi_pt2(accA, A32, 0);
    epi_pt2(accB, A32, 1);
    // pair 1
    mfma_pair2(accA, accB, wf4, afA, afB, bv4);
    read_af8(afA, B32, 4);
    read_af8(afB, B32, 5);
    __builtin_amdgcn_sched_barrier(0);
#pragma unroll
    for (int ks = 0; ks < 8; ++ks)  // wf5: 32 regs (col tile = wlo)
      wf5[ks] = *reinterpret_cast<const bf16x8*>(
          wb + OFF_W5 + (wlo * 16 + l15) * 256 + ks * 32 + quad * 8);
    bv5 = *reinterpret_cast<const f32x4*>(bws + 960 + wlo * 16 + quad * 4);
    epi_pt2(accA, A32, 2);
    epi_pt2(accB, A32, 3);
    // pair 2
    mfma_pair2(accA, accB, wf4, afA, afB, bv4);
    read_af8(afA, B32, 6);
    read_af8(afB, B32, 7);
    epi_pt2(accA, A32, 4);
    epi_pt2(accB, A32, 5);
    // pair 3
    mfma_pair2(accA, accB, wf4, afA, afB, bv4);
    epi_pt2(accA, A32, 6);
    epi_pt2(accB, A32, 7);
  }
  lds_barrier();

  // ---------- L5: A32 -> global (wave: pts p0..p0+3, col tile wlo) ----------
  {
    float* out_base = out + (size_t)(c * 2 + bq) * 64 * kHW + hw0;
    const int o = wlo * 16 + quad * 4;
    bf16x8 afA[8], afB[8];
    read_af8(afA, A32, p0);
    read_af8(afB, A32, p0 + 1);
#pragma unroll
    for (int pp = 0; pp < 2; ++pp) {
      f32x4 accA = bv5, accB = bv5;
#pragma unroll
      for (int ks = 0; ks < 8; ++ks) {
        accA = mf(wf5[ks], afA[ks], accA);
        accB = mf(wf5[ks], afB[ks], accB);
      }
      if (pp == 0) { read_af8(afA, A32, p0 + 2); read_af8(afB, A32, p0 + 3); }
      const int ptA = p0 + pp * 2, ptB = p0 + pp * 2 + 1;
      float* dstA = out_base + (size_t)o * kHW + (ptA * 16 + l15);
      float* dstB = out_base + (size_t)o * kHW + (ptB * 16 + l15);
#pragma unroll
      for (int r = 0; r < 4; ++r) dstA[(size_t)r * kHW] = accA[r];
#pragma unroll
      for (int r = 0; r < 4; ++r) dstB[(size_t)r * kHW] = accB[r];
    }
  }
}

extern "C" void kernel_launch(void* const* d_in, const int* in_sizes, int n_in,
                              void* d_out, int out_size, void* d_ws, size_t ws_size,
                              hipStream_t stream) {
  const float* feat  = (const float*)d_in[0];
  const float* times = (const float*)d_in[1];
  const float* w0 = (const float*)d_in[2];
  const float* b0 = (const float*)d_in[3];
  const float* w1 = (const float*)d_in[4];
  const float* b1 = (const float*)d_in[5];
  const float* w2 = (const float*)d_in[6];
  const float* b2 = (const float*)d_in[7];
  const float* w3 = (const float*)d_in[8];
  const float* b3 = (const float*)d_in[9];
  const float* w4 = (const float*)d_in[10];
  const float* b4 = (const float*)d_in[11];
  const float* w5 = (const float*)d_in[12];
  const float* b5 = (const float*)d_in[13];
  u16*   wb  = (u16*)d_ws;
  float* bws = (float*)((char*)d_ws + (size_t)W_TOTAL * 2);
  float* out = (float*)d_out;

  convert_weights<<<(W_TOTAL + B_TOTAL) / 256, 256, 0, stream>>>(
      w0, w1, w2, w3, w4, w5, b0, b1, b2, b3, b4, b5, wb, bws);

  if (ws_size >= WS_NEED) {
    u16* featT = (u16*)((char*)d_ws + FEAT_BYTE_OFF);
    convert_feat<<<1920, 256, 0, stream>>>(feat, featT);
    siren_main<true><<<2880, 512, 0, stream>>>(feat, times, wb, bws, featT, out);
  } else {
    siren_main<false><<<2880, 512, 0, stream>>>(feat, times, wb, bws, wb, out);
  }
}